// Round 9
// baseline (1783.244 us; speedup 1.0000x reference)
//
#include <hip/hip_runtime.h>

#define BB 8
#define NN 4096
#define KK 20
constexpr float EPSV = 1e-5f;
constexpr float SLOPE = 0.2f;

typedef __bf16 bfrag __attribute__((ext_vector_type(8)));
typedef float floatx4 __attribute__((ext_vector_type(4)));
typedef unsigned short us4 __attribute__((ext_vector_type(4)));
typedef unsigned short us8 __attribute__((ext_vector_type(8)));

__device__ __forceinline__ float lrelu(float v) { return v >= 0.f ? v : SLOPE * v; }

__device__ __forceinline__ unsigned short bf16rn(float f) {
    unsigned int u = __float_as_uint(f);
    return (unsigned short)((u + 0x7FFFu + ((u >> 16) & 1u)) >> 16);
}
__device__ __forceinline__ float bf16up(unsigned short h) {
    return __uint_as_float(((unsigned int)h) << 16);
}

// async global->LDS DMA, 16B per lane; lds dest must be wave-uniform base.
__device__ __forceinline__ void gl_lds16(const unsigned short* g, unsigned short* l) {
    __builtin_amdgcn_global_load_lds((const __attribute__((address_space(1))) void*)g,
                                     (__attribute__((address_space(3))) void*)l, 16, 0, 0);
}

// counted vm wait (assembler handles encoding); N is compile-time.
template<int N> __device__ __forceinline__ void wait_vm() {
    if constexpr (N == 0)      asm volatile("s_waitcnt vmcnt(0)");
    else if constexpr (N == 1) asm volatile("s_waitcnt vmcnt(1)");
    else if constexpr (N == 2) asm volatile("s_waitcnt vmcnt(2)");
    else if constexpr (N == 3) asm volatile("s_waitcnt vmcnt(3)");
    else if constexpr (N == 4) asm volatile("s_waitcnt vmcnt(4)");
    else                       asm volatile("s_waitcnt vmcnt(5)");
}
__device__ __forceinline__ void wait_lgkm0() {
    asm volatile("s_waitcnt lgkmcnt(0)" ::: "memory");
}

__global__ void zero_kernel(float* p, int n) {
    int i = blockIdx.x * 256 + threadIdx.x;
    if (i < n) p[i] = 0.f;
}

// 0.5*||x_n||^2 per point (exact fp32). grid (NN/256, BB), block 256.
template<int C>
__global__ void halfnorm_kernel(const float* __restrict__ src, float* __restrict__ hng) {
    int n = blockIdx.x * 256 + threadIdx.x;
    int b = blockIdx.y;
    float s = 0.f;
    #pragma unroll
    for (int c = 0; c < C; c++) { float v = src[(b * C + c) * NN + n]; s += v * v; }
    hng[b * NN + n] = 0.5f * s;
}

// ---------------- one-shot bf16 hi/lo pack (C>=32) ----------------
// pk[(b*NN+m)*SK + k]: [0,C)=hi; [C,2C)=lo; [2C,2C+2)=hn fp32 bits; rest 0.
// MFMA fragments only read [0,2C) so the hn pad never enters the matmul.
template<int C>
__global__ void pack_kernel(const float* __restrict__ src, const float* __restrict__ hng,
                            unsigned short* __restrict__ pk) {
    constexpr int SK = 2 * C + 8;
    const int b = blockIdx.y;
    const int m0 = blockIdx.x * 64;
    const int tid = threadIdx.x;
    for (int i = tid; i < 64 * (C / 4); i += 256) {
        int m = i & 63;
        int c4 = (i >> 6) * 4;
        us4 hv, lv;
        #pragma unroll
        for (int j = 0; j < 4; j++) {
            float v = src[(b * C + c4 + j) * NN + m0 + m];
            unsigned short h = bf16rn(v);
            hv[j] = h;
            lv[j] = bf16rn(v - bf16up(h));
        }
        *(us4*)(&pk[(size_t)(b * NN + m0 + m) * SK + c4]) = hv;
        *(us4*)(&pk[(size_t)(b * NN + m0 + m) * SK + C + c4]) = lv;
    }
    if (tid < 64) {
        unsigned int ub = __float_as_uint(hng[b * NN + m0 + tid]);
        us8 z;
        #pragma unroll
        for (int j = 0; j < 8; j++) z[j] = 0;
        z[0] = (unsigned short)(ub & 0xFFFFu);
        z[1] = (unsigned short)(ub >> 16);
        *(us8*)(&pk[(size_t)(b * NN + m0 + tid) * SK + 2 * C]) = z;
    }
}

// C=3 B-pack: [h3 l3 l3 h3 | 0 x20 | hn fp32 | 0 x6] per point (SK=40).
// B fragments read k in [0,32) only; hn pad at [32,34) untouched by MFMA.
__global__ void pack3_kernel(const float* __restrict__ src, const float* __restrict__ hng,
                             unsigned short* __restrict__ pk) {
    const int b = blockIdx.y;
    const int m = blockIdx.x * 256 + threadIdx.x;
    us8 w0, w1;
    #pragma unroll
    for (int j = 0; j < 8; j++) { w0[j] = 0; w1[j] = 0; }
    unsigned short row[12];
    #pragma unroll
    for (int c = 0; c < 3; c++) {
        float v = src[(b * 3 + c) * NN + m];
        unsigned short h = bf16rn(v);
        unsigned short l = bf16rn(v - bf16up(h));
        row[c] = h; row[3 + c] = l; row[6 + c] = l; row[9 + c] = h;
    }
    #pragma unroll
    for (int j = 0; j < 8; j++) w0[j] = row[j];
    #pragma unroll
    for (int j = 0; j < 4; j++) w1[j] = row[8 + j];
    unsigned short* dst = pk + (size_t)(b * NN + m) * 40;
    us8 z;
    #pragma unroll
    for (int j = 0; j < 8; j++) z[j] = 0;
    unsigned int ub = __float_as_uint(hng[b * NN + m]);
    us8 zh = z;
    zh[0] = (unsigned short)(ub & 0xFFFFu);
    zh[1] = (unsigned short)(ub >> 16);
    *(us8*)(dst) = w0;
    *(us8*)(dst + 8) = w1;
    *(us8*)(dst + 16) = z;
    *(us8*)(dst + 24) = z;
    *(us8*)(dst + 32) = zh;
}

// ---------------- kNN via MFMA (bf16 hi/lo split, 4-term exact) ----------------
// Round-9: round-7 geometry (64 q/block, 2 blocks/CU, pool + tid<64 drain, exact
// tau, DMA dbuf staging, hn in pad, XCD pin) with T4 counted-vmcnt discipline:
//  * raw s_barrier (no implicit vmcnt(0) drain) at B1/B2.
//  * DMA(ch+2) issued in phase B into the buffer freed at B1; before B2 each
//    wave waits vmcnt(own ch+2 count) -> DMA(ch+1) wave-locally retired; the
//    barrier makes it a group guarantee (m201 pattern). Phase A has NO vm wait.
//  * B1 = lgkmcnt(0)+barrier only (pool visibility).
template<int C>
__global__ __launch_bounds__(256) void knn_kernel(const float* __restrict__ src,
                                                  const unsigned short* __restrict__ pk,
                                                  int* __restrict__ idx) {
    constexpr int SK = (C == 3) ? 40 : (2 * C + 8);   // padded k-stride (shorts)
    constexpr int HNOFF = (C == 3) ? 32 : 2 * C;      // hn fp32 offset in row
    constexpr int UNITS = 8 * SK;                     // 16B units per 64-row chunk
    constexpr int CHUNK = 64 * SK;                    // shorts per staging buffer
    constexpr int RU = (UNITS + 255) / 256;           // wave0 issues RU, waves1-3 RU-1
    constexpr int KKN = (C == 3) ? 1 : (C / 32);
    __shared__ __attribute__((aligned(16))) unsigned short cpack[2 * CHUNK];
    __shared__ float pv[64 * 65];
    __shared__ unsigned short pidx[64 * 66];
    __shared__ float tau[64];
    __shared__ int cnt[64];
    __shared__ unsigned short qls[(C == 3) ? 64 * 40 : 2];

    const int bid = blockIdx.x;
    const int b = bid & 7;               // batch -> XCD (wgid % 8 round-robin)
    const int q0 = (bid >> 3) * 64;
    const int tid = threadIdx.x;
    const int lane = tid & 63;
    const int wv = tid >> 6;
    const int wr = (wv >> 1) * 32;      // wave q-offset in [0,64)
    const int wc = (wv & 1) * 32;       // wave m-offset in [0,64)
    const int fl = lane & 15;
    const int fq = lane >> 4;

    float tv[20]; int ti[20];
    #pragma unroll
    for (int k = 0; k < 20; k++) { tv[k] = -3.4e38f; ti[k] = 0; }

    // ---- A fragments (registers, once) ----
    bfrag qah[KKN][2], qal[KKN][2];
    if (C == 3) {
        for (int i = tid; i < 64 * 20; i += 256) {
            int r = i / 20, k = 12 + i % 20;
            qls[r * 40 + k] = 0;
        }
        if (tid < 64) {
            #pragma unroll
            for (int c = 0; c < 3; c++) {
                float v = src[(b * 3 + c) * NN + q0 + tid];
                unsigned short h = bf16rn(v);
                unsigned short l = bf16rn(v - bf16up(h));
                // A-pack: [h3 l3 h3 l3 | 0...] pairs with B-pack [h3 l3 l3 h3]
                qls[tid * 40 + c] = h;  qls[tid * 40 + 3 + c] = l;
                qls[tid * 40 + 6 + c] = h;  qls[tid * 40 + 9 + c] = l;
            }
        }
    } else {
        #pragma unroll
        for (int r2 = 0; r2 < 2; r2++) {
            const unsigned short* qr = pk + (size_t)(b * NN + q0 + wr + r2 * 16 + fl) * SK + fq * 8;
            #pragma unroll
            for (int kk = 0; kk < KKN; kk++) {
                qah[kk][r2] = *(const bfrag*)(qr + kk * 32);
                qal[kk][r2] = *(const bfrag*)(qr + C + kk * 32);
            }
        }
    }

    // ---- prologue: async-stage chunk 0 -> buf0 and chunk 1 -> buf1 ----
    {
        const unsigned short* p0 = pk + (size_t)(b * NN) * SK;
        #pragma unroll
        for (int r = 0; r < RU; r++) {
            int u0 = r * 256 + wv * 64;
            if (u0 < UNITS)
                gl_lds16(p0 + (size_t)(u0 + lane) * 8, cpack + (size_t)u0 * 8);
        }
        const unsigned short* p1 = pk + (size_t)(b * NN + 64) * SK;
        #pragma unroll
        for (int r = 0; r < RU; r++) {
            int u0 = r * 256 + wv * 64;
            if (u0 < UNITS)
                gl_lds16(p1 + (size_t)(u0 + lane) * 8, cpack + (size_t)(CHUNK * 1) + (size_t)u0 * 8 - CHUNK + CHUNK);
        }
    }
    if (tid < 64) { tau[tid] = -3.4e38f; cnt[tid] = 0; }
    // wave-local: ensure chunk-0 DMAs retired (allow chunk-1 set in flight), then join.
    wait_lgkm0();
    if (wv == 0) wait_vm<RU>(); else wait_vm<RU - 1>();
    __builtin_amdgcn_s_barrier();

    bfrag qa3[2];
    if (C == 3) {
        #pragma unroll
        for (int r2 = 0; r2 < 2; r2++)
            qa3[r2] = *(const bfrag*)(&qls[(wr + r2 * 16 + fl) * 40 + fq * 8]);
    }

    for (int ch = 0; ch < 64; ch++) {
        const unsigned short* cur = cpack + (ch & 1) * CHUNK;

        // ---- phase A: MFMA on cur (no vm wait needed: guaranteed at prev B2) ----
        floatx4 acc[2][2];
        #pragma unroll
        for (int r2 = 0; r2 < 2; r2++)
            #pragma unroll
            for (int c2 = 0; c2 < 2; c2++)
                acc[r2][c2] = (floatx4)(0.f);

        if (C == 3) {
            #pragma unroll
            for (int c2 = 0; c2 < 2; c2++) {
                bfrag bm = *(const bfrag*)(&cur[(wc + c2 * 16 + fl) * SK + fq * 8]);
                #pragma unroll
                for (int r2 = 0; r2 < 2; r2++)
                    acc[r2][c2] = __builtin_amdgcn_mfma_f32_16x16x32_bf16(qa3[r2], bm, acc[r2][c2], 0, 0, 0);
            }
        } else {
            #pragma unroll
            for (int kk = 0; kk < KKN; kk++) {
                const int kb = kk * 32 + fq * 8;
                bfrag bh[2], bl[2];
                #pragma unroll
                for (int c2 = 0; c2 < 2; c2++) {
                    bh[c2] = *(const bfrag*)(&cur[(wc + c2 * 16 + fl) * SK + kb]);
                    bl[c2] = *(const bfrag*)(&cur[(wc + c2 * 16 + fl) * SK + C + kb]);
                }
                #pragma unroll
                for (int r2 = 0; r2 < 2; r2++)
                    #pragma unroll
                    for (int c2 = 0; c2 < 2; c2++) {
                        acc[r2][c2] = __builtin_amdgcn_mfma_f32_16x16x32_bf16(qah[kk][r2], bh[c2], acc[r2][c2], 0, 0, 0);
                        acc[r2][c2] = __builtin_amdgcn_mfma_f32_16x16x32_bf16(qah[kk][r2], bl[c2], acc[r2][c2], 0, 0, 0);
                        acc[r2][c2] = __builtin_amdgcn_mfma_f32_16x16x32_bf16(qal[kk][r2], bh[c2], acc[r2][c2], 0, 0, 0);
                        acc[r2][c2] = __builtin_amdgcn_mfma_f32_16x16x32_bf16(qal[kk][r2], bl[c2], acc[r2][c2], 0, 0, 0);
                    }
            }
        }

        // ---- filter: C-layout col=lane&15 (m), row=fq*4+reg (q); exact tau;
        //      hn read from the staged row pad in LDS ----
        {
            const int m0 = ch * 64;
            float hvv[2];
            #pragma unroll
            for (int c2 = 0; c2 < 2; c2++)
                hvv[c2] = *(const float*)(&cur[(wc + c2 * 16 + fl) * SK + HNOFF]);
            #pragma unroll
            for (int r2 = 0; r2 < 2; r2++) {
                const int qb = wr + r2 * 16 + fq * 4;
                float4 t4 = *(const float4*)(&tau[qb]);
                float ta[4] = { t4.x, t4.y, t4.z, t4.w };
                #pragma unroll
                for (int c2 = 0; c2 < 2; c2++) {
                    const float hv = hvv[c2];
                    const int mm = m0 + wc + c2 * 16 + fl;
                    #pragma unroll
                    for (int reg = 0; reg < 4; reg++) {
                        float s = acc[r2][c2][reg] - hv;
                        if (s > ta[reg]) {
                            int q = qb + reg;
                            int p = atomicAdd(&cnt[q], 1);   // <= 64 per chunk: fits
                            pv[q * 65 + p] = s;
                            pidx[q * 66 + p] = (unsigned short)mm;
                        }
                    }
                }
            }
        }
        wait_lgkm0();                      // own pool writes drained
        __builtin_amdgcn_s_barrier();      // B1: pool visible; cur reads finished; NO vm drain

        // ---- phase B: issue DMA(ch+2) into the freed buffer; drain pool ----
        if (ch + 2 < 64) {
            unsigned short* dst = cpack + (ch & 1) * CHUNK;   // cur buffer, now free
            const unsigned short* pn = pk + (size_t)(b * NN + (ch + 2) * 64) * SK;
            #pragma unroll
            for (int r = 0; r < RU; r++) {
                int u0 = r * 256 + wv * 64;
                if (u0 < UNITS)
                    gl_lds16(pn + (size_t)(u0 + lane) * 8, dst + (size_t)u0 * 8);
            }
        }
        if (tid < 64) {
            int n = cnt[tid];
            for (int t = 0; t < n; t++) {
                float v = pv[tid * 65 + t];
                if (v > tv[0]) {
                    tv[0] = v; ti[0] = (int)pidx[tid * 66 + t];
                    #pragma unroll
                    for (int j = 0; j < 19; j++) {
                        if (tv[j] > tv[j + 1]) {
                            float a = tv[j]; tv[j] = tv[j + 1]; tv[j + 1] = a;
                            int bi = ti[j]; ti[j] = ti[j + 1]; ti[j + 1] = bi;
                        }
                    }
                }
            }
            cnt[tid] = 0;
            tau[tid] = tv[0];
        }
        // wave-local: ensure DMA(ch+1) retired (allow DMA(ch+2) in flight), then join.
        wait_lgkm0();
        if (ch + 1 < 64) {
            if (ch + 2 < 64) { if (wv == 0) wait_vm<RU>(); else wait_vm<RU - 1>(); }
            else             wait_vm<0>();
        }
        __builtin_amdgcn_s_barrier();      // B2: tau/cnt visible; next chunk resident
    }

    if (tid < 64) {
        #pragma unroll
        for (int k = 0; k < 20; k++)
            idx[(b * NN + q0 + tid) * KK + k] = ti[k];   // order irrelevant downstream
    }
}

// ---------------- conv precompute: G = Wd*src, H = (Wc-Wd)*src ----------------
template<int COUT>
__global__ void precompute_kernel(const float* __restrict__ src, int C,
                                  const float* __restrict__ w, int CIN, int wd_off, int wc_off,
                                  float* __restrict__ G, float* __restrict__ H,
                                  int initG, int initH) {
    constexpr int MY = 256 / COUT;
    extern __shared__ float lds[];
    float* wd = lds;
    float* wc = lds + C * COUT;
    const int b = blockIdx.y;
    const int tid = threadIdx.y * COUT + threadIdx.x;
    for (int i = tid; i < C * COUT; i += 256) {
        int c = i / COUT, o = i % COUT;
        float a  = w[o * CIN + wd_off + c];
        float cc = w[o * CIN + wc_off + c];
        wd[i] = a;
        wc[i] = cc - a;
    }
    __syncthreads();
    const int o = threadIdx.x;
    for (int it = 0; it < COUT / 4; it++) {
        int m = blockIdx.x * 64 + it * MY + threadIdx.y;
        float g = 0.f, h = 0.f;
        for (int c = 0; c < C; c++) {
            float s = src[(b * C + c) * NN + m];
            g += wd[c * COUT + o] * s;
            h += wc[c * COUT + o] * s;
        }
        int gi = (b * NN + m) * COUT + o;
        if (initG) G[gi] = g; else G[gi] += g;
        if (initH) H[gi] = h; else H[gi] += h;
    }
}

// ---------------- conv stats + per-(b,n,o) min/max over k ----------------
template<int COUT, int GROUPS>
__global__ void conv_stats_kernel(const float* __restrict__ G1, const int* __restrict__ idx1,
                                  const float* __restrict__ G2, const int* __restrict__ idx2,
                                  const float* __restrict__ H, float* __restrict__ stats,
                                  float* __restrict__ MaxY, float* __restrict__ MinY) {
    constexpr int NY = 256 / COUT;
    const int b = blockIdx.y;
    const int o = threadIdx.x;
    const int n = blockIdx.x * NY + threadIdx.y;
    const int base = b * NN + n;
    const float h = H[base * COUT + o];
    float s1 = 0.f, s2 = 0.f;
    float gx = -3.4e38f, gn = 3.4e38f;
    #pragma unroll
    for (int k = 0; k < KK; k++) {
        int i1 = idx1[base * KK + k];
        float g = G1[(b * NN + i1) * COUT + o];
        if (GROUPS == 2) {
            int i2 = idx2[base * KK + k];
            g += G2[(b * NN + i2) * COUT + o];
        }
        float y = g + h;
        s1 += y;
        s2 += y * y;
        gx = fmaxf(gx, g);
        gn = fminf(gn, g);
    }
    MaxY[base * COUT + o] = gx + h;
    MinY[base * COUT + o] = gn + h;

    __shared__ float ls[2 * COUT];
    if (threadIdx.y == 0) { ls[o] = 0.f; ls[COUT + o] = 0.f; }
    __syncthreads();
    atomicAdd(&ls[o], s1);
    atomicAdd(&ls[COUT + o], s2);
    __syncthreads();
    if (threadIdx.y == 0) {
        atomicAdd(&stats[o], ls[o]);
        atomicAdd(&stats[64 + o], ls[COUT + o]);
    }
}

__global__ void finalize_kernel(const float* __restrict__ g, const float* __restrict__ bb,
                                float* __restrict__ stats, int cout, float invP) {
    int o = threadIdx.x;
    if (o >= cout) return;
    float mu  = stats[o] * invP;
    float var = stats[64 + o] * invP - mu * mu;
    float sc  = g[o] * rsqrtf(var + EPSV);
    stats[128 + o] = sc;
    stats[192 + o] = bb[o] - mu * sc;
}

__global__ void apply_kernel(const float* __restrict__ MaxY, const float* __restrict__ MinY,
                             const float* __restrict__ stats, float* __restrict__ out, int cout) {
    int e = blockIdx.x * 256 + threadIdx.x;
    int total = BB * cout * NN;
    if (e >= total) return;
    int n = e & (NN - 1);
    int o = (e >> 12) % cout;
    int b = e / (NN * cout);
    float sc = stats[128 + o], sh = stats[192 + o];
    int si = (b * NN + n) * cout + o;
    float v = (sc >= 0.f) ? MaxY[si] : MinY[si];
    out[e] = lrelu(sc * v + sh);
}

__global__ void mean_kernel(const float* __restrict__ xd1, const float* __restrict__ xd2,
                            float* __restrict__ hsum) {
    __shared__ float bins[128];
    const int tid = threadIdx.x;
    if (tid < 128) bins[tid] = 0.f;
    __syncthreads();
    const int half = BB * 64 * NN;
    const int stride = gridDim.x * 256;
    for (int e = blockIdx.x * 256 + tid; e < half; e += stride)
        atomicAdd(&bins[e & 127], xd1[e]);
    for (int e = blockIdx.x * 256 + tid; e < half; e += stride)
        atomicAdd(&bins[e & 127], xd2[e]);
    __syncthreads();
    if (tid < 128) atomicAdd(&hsum[tid], bins[tid]);
}

__global__ void head_kernel(const float* __restrict__ hsum,
                            const float* __restrict__ W2d, const float* __restrict__ b2d,
                            const float* __restrict__ W3d, const float* __restrict__ b3d,
                            const float* __restrict__ W4d, const float* __restrict__ b4d,
                            float* __restrict__ out) {
    __shared__ float h[128], t1[128], t2[64];
    const int t = threadIdx.x;
    h[t] = hsum[t] * (1.f / 32768.f);
    __syncthreads();
    float a = b2d[t];
    for (int j = 0; j < 128; j++) a += W2d[t * 128 + j] * h[j];
    t1[t] = lrelu(a);
    __syncthreads();
    if (t < 64) {
        float a2 = b3d[t];
        for (int j = 0; j < 128; j++) a2 += W3d[t * 128 + j] * t1[j];
        t2[t] = lrelu(a2);
    }
    __syncthreads();
    if (t < 11) {
        float a3 = b4d[t];
        for (int j = 0; j < 64; j++) a3 += W4d[t * 64 + j] * t2[j];
        out[t] = lrelu(a3);
    }
}

extern "C" void kernel_launch(void* const* d_in, const int* in_sizes, int n_in,
                              void* d_out, int out_size, void* d_ws, size_t ws_size,
                              hipStream_t stream) {
    const float* x   = (const float*)d_in[0];
    const float* w1  = (const float*)d_in[1];
    const float* g1  = (const float*)d_in[2];
    const float* b1  = (const float*)d_in[3];
    const float* w2  = (const float*)d_in[4];
    const float* g2  = (const float*)d_in[5];
    const float* b2  = (const float*)d_in[6];
    const float* wd1 = (const float*)d_in[7];
    const float* gd1 = (const float*)d_in[8];
    const float* bd1 = (const float*)d_in[9];
    const float* wd2 = (const float*)d_in[10];
    const float* gd2 = (const float*)d_in[11];
    const float* bd2 = (const float*)d_in[12];
    const float* W2d = (const float*)d_in[13];
    const float* b2d = (const float*)d_in[14];
    const float* W3d = (const float*)d_in[15];
    const float* b3d = (const float*)d_in[16];
    const float* W4d = (const float*)d_in[17];
    const float* b4d = (const float*)d_in[18];
    float* out = (float*)d_out;

    char* ws = (char*)d_ws;
    size_t off = 0;
    auto alloc = [&](size_t bytes) { char* p = ws + off; off += (bytes + 255) & ~size_t(255); return p; };
    int*   idx1  = (int*)  alloc(BB * NN * KK * 4);
    int*   idx2  = (int*)  alloc(BB * NN * KK * 4);
    int*   idx3  = (int*)  alloc(BB * NN * KK * 4);
    float* x1m   = (float*)alloc(BB * 32 * NN * 4);
    float* x2m   = (float*)alloc(BB * 64 * NN * 4);
    float* xd1   = (float*)alloc(BB * 64 * NN * 4);
    float* xd2   = (float*)alloc(BB * 64 * NN * 4);
    float* G1    = (float*)alloc((size_t)BB * NN * 64 * 4);
    float* G2    = (float*)alloc((size_t)BB * NN * 64 * 4);
    float* H     = (float*)alloc((size_t)BB * NN * 64 * 4);
    float* MaxY  = (float*)alloc((size_t)BB * NN * 64 * 4);
    float* MinY  = (float*)alloc((size_t)BB * NN * 64 * 4);
    float* stats = (float*)alloc(256 * 4);
    float* hsum  = (float*)alloc(128 * 4);
    float* hng   = (float*)alloc(BB * NN * 4);

    // pk scratch reuses MaxY (+ start of MinY for C=64); dead at every kNN site.
    unsigned short* pkbuf = (unsigned short*)MaxY;

    const float invP = 1.f / (float)(BB * NN * KK);
    const dim3 knn_grid(NN / 64 * BB);     // 1D: b = id & 7 (XCD pinning), q0 = (id>>3)*64
    const dim3 hn_grid(NN / 256, BB);

    zero_kernel<<<1, 256, 0, stream>>>(hsum, 128);

    // --- kNN on x (C=3) ---
    halfnorm_kernel<3><<<hn_grid, 256, 0, stream>>>(x, hng);
    pack3_kernel<<<dim3(NN / 256, BB), 256, 0, stream>>>(x, hng, pkbuf);
    knn_kernel<3><<<knn_grid, 256, 0, stream>>>(x, pkbuf, idx1);

    // --- conv1: Cout=32, group (x, idx1, C=3), w1 CIN=6 ---
    zero_kernel<<<1, 256, 0, stream>>>(stats, 128);
    precompute_kernel<32><<<dim3(NN / 64, BB), dim3(32, 8), 2 * 3 * 32 * 4, stream>>>(
        x, 3, w1, 6, 0, 3, G1, H, 1, 1);
    conv_stats_kernel<32, 1><<<dim3(NN / 8, BB), dim3(32, 8), 0, stream>>>(
        G1, idx1, nullptr, nullptr, H, stats, MaxY, MinY);
    finalize_kernel<<<1, 64, 0, stream>>>(g1, b1, stats, 32, invP);
    apply_kernel<<<(BB * 32 * NN + 255) / 256, 256, 0, stream>>>(MaxY, MinY, stats, x1m, 32);

    // --- kNN on x1_max (C=32) ---
    halfnorm_kernel<32><<<hn_grid, 256, 0, stream>>>(x1m, hng);
    pack_kernel<32><<<dim3(NN / 64, BB), 256, 0, stream>>>(x1m, hng, pkbuf);
    knn_kernel<32><<<knn_grid, 256, 0, stream>>>(x1m, pkbuf, idx2);

    // --- conv2: Cout=64, groups (x, idx1, 3) + (x1m, idx2, 32), w2 CIN=70 ---
    zero_kernel<<<1, 256, 0, stream>>>(stats, 128);
    precompute_kernel<64><<<dim3(NN / 64, BB), dim3(64, 4), 2 * 3 * 64 * 4, stream>>>(
        x, 3, w2, 70, 0, 3, G1, H, 1, 1);
    precompute_kernel<64><<<dim3(NN / 64, BB), dim3(64, 4), 2 * 32 * 64 * 4, stream>>>(
        x1m, 32, w2, 70, 6, 38, G2, H, 1, 0);
    conv_stats_kernel<64, 2><<<dim3(NN / 4, BB), dim3(64, 4), 0, stream>>>(
        G1, idx1, G2, idx2, H, stats, MaxY, MinY);
    finalize_kernel<<<1, 64, 0, stream>>>(g2, b2, stats, 64, invP);
    apply_kernel<<<(BB * 64 * NN + 255) / 256, 256, 0, stream>>>(MaxY, MinY, stats, x2m, 64);

    // --- convd1: Cout=64, group (x1m, idx2, 32), wd1 CIN=64 ---
    zero_kernel<<<1, 256, 0, stream>>>(stats, 128);
    precompute_kernel<64><<<dim3(NN / 64, BB), dim3(64, 4), 2 * 32 * 64 * 4, stream>>>(
        x1m, 32, wd1, 64, 0, 32, G1, H, 1, 1);
    conv_stats_kernel<64, 1><<<dim3(NN / 4, BB), dim3(64, 4), 0, stream>>>(
        G1, idx2, nullptr, nullptr, H, stats, MaxY, MinY);
    finalize_kernel<<<1, 64, 0, stream>>>(gd1, bd1, stats, 64, invP);
    apply_kernel<<<(BB * 64 * NN + 255) / 256, 256, 0, stream>>>(MaxY, MinY, stats, xd1, 64);

    // --- kNN on x2_max (C=64) ---
    halfnorm_kernel<64><<<hn_grid, 256, 0, stream>>>(x2m, hng);
    pack_kernel<64><<<dim3(NN / 64, BB), 256, 0, stream>>>(x2m, hng, pkbuf);
    knn_kernel<64><<<knn_grid, 256, 0, stream>>>(x2m, pkbuf, idx3);

    // --- convd2: Cout=64, group (x2m, idx3, 64), wd2 CIN=128 ---
    zero_kernel<<<1, 256, 0, stream>>>(stats, 128);
    precompute_kernel<64><<<dim3(NN / 64, BB), dim3(64, 4), 2 * 64 * 64 * 4, stream>>>(
        x2m, 64, wd2, 128, 0, 64, G1, H, 1, 1);
    conv_stats_kernel<64, 1><<<dim3(NN / 4, BB), dim3(64, 4), 0, stream>>>(
        G1, idx3, nullptr, nullptr, H, stats, MaxY, MinY);
    finalize_kernel<<<1, 64, 0, stream>>>(gd2, bd2, stats, 64, invP);
    apply_kernel<<<(BB * 64 * NN + 255) / 256, 256, 0, stream>>>(MaxY, MinY, stats, xd2, 64);

    // --- global mean + MLP head ---
    mean_kernel<<<1024, 256, 0, stream>>>(xd1, xd2, hsum);
    head_kernel<<<1, 128, 0, stream>>>(hsum, W2d, b2d, W3d, b3d, W4d, b4d, out);
}

// Round 10
// 1669.552 us; speedup vs baseline: 1.0681x; 1.0681x over previous
//
#include <hip/hip_runtime.h>

#define BB 8
#define NN 4096
#define KK 20
constexpr float EPSV = 1e-5f;
constexpr float SLOPE = 0.2f;

typedef __bf16 bfrag __attribute__((ext_vector_type(8)));
typedef float floatx4 __attribute__((ext_vector_type(4)));
typedef unsigned short us4 __attribute__((ext_vector_type(4)));
typedef unsigned short us8 __attribute__((ext_vector_type(8)));

__device__ __forceinline__ float lrelu(float v) { return v >= 0.f ? v : SLOPE * v; }

__device__ __forceinline__ unsigned short bf16rn(float f) {
    unsigned int u = __float_as_uint(f);
    return (unsigned short)((u + 0x7FFFu + ((u >> 16) & 1u)) >> 16);
}
__device__ __forceinline__ float bf16up(unsigned short h) {
    return __uint_as_float(((unsigned int)h) << 16);
}

// async global->LDS DMA, 16B per lane; lds dest must be wave-uniform base.
__device__ __forceinline__ void gl_lds16(const unsigned short* g, unsigned short* l) {
    __builtin_amdgcn_global_load_lds((const __attribute__((address_space(1))) void*)g,
                                     (__attribute__((address_space(3))) void*)l, 16, 0, 0);
}

__global__ void zero_kernel(float* p, int n) {
    int i = blockIdx.x * 256 + threadIdx.x;
    if (i < n) p[i] = 0.f;
}

// ---------------- one-shot bf16 hi/lo pack (C>=32), hn fused ----------------
// pk[(b*NN+m)*SK + k]: [0,C)=hi; [C,2C)=lo; [2C,2C+2)=hn fp32 bits; rest 0.
// MFMA fragments only read [0,2C) so the hn pad never enters the matmul.
// XCD-pinned: b = blockIdx.x & 7. hn computed inline (halfnorm kernel removed).
template<int C>
__global__ void pack_kernel(const float* __restrict__ src, unsigned short* __restrict__ pk) {
    constexpr int SK = 2 * C + 8;
    const int id = blockIdx.x;
    const int b = id & 7;
    const int m0 = (id >> 3) * 64;
    const int tid = threadIdx.x;
    for (int i = tid; i < 64 * (C / 4); i += 256) {
        int m = i & 63;
        int c4 = (i >> 6) * 4;
        us4 hv, lv;
        #pragma unroll
        for (int j = 0; j < 4; j++) {
            float v = src[(b * C + c4 + j) * NN + m0 + m];
            unsigned short h = bf16rn(v);
            hv[j] = h;
            lv[j] = bf16rn(v - bf16up(h));
        }
        *(us4*)(&pk[(size_t)(b * NN + m0 + m) * SK + c4]) = hv;
        *(us4*)(&pk[(size_t)(b * NN + m0 + m) * SK + C + c4]) = lv;
    }
    if (tid < 64) {
        float s = 0.f;
        for (int c = 0; c < C; c++) {
            float v = src[(b * C + c) * NN + m0 + tid];
            s += v * v;
        }
        unsigned int ub = __float_as_uint(0.5f * s);
        us8 z;
        #pragma unroll
        for (int j = 0; j < 8; j++) z[j] = 0;
        z[0] = (unsigned short)(ub & 0xFFFFu);
        z[1] = (unsigned short)(ub >> 16);
        *(us8*)(&pk[(size_t)(b * NN + m0 + tid) * SK + 2 * C]) = z;
    }
}

// C=3 B-pack: [h3 l3 l3 h3 | 0 x20 | hn fp32 | 0 x6] per point (SK=40), hn inline.
__global__ void pack3_kernel(const float* __restrict__ src, unsigned short* __restrict__ pk) {
    const int id = blockIdx.x;
    const int b = id & 7;
    const int m = (id >> 3) * 256 + threadIdx.x;
    us8 w0, w1;
    #pragma unroll
    for (int j = 0; j < 8; j++) { w0[j] = 0; w1[j] = 0; }
    unsigned short row[12];
    float s = 0.f;
    #pragma unroll
    for (int c = 0; c < 3; c++) {
        float v = src[(b * 3 + c) * NN + m];
        s += v * v;
        unsigned short h = bf16rn(v);
        unsigned short l = bf16rn(v - bf16up(h));
        row[c] = h; row[3 + c] = l; row[6 + c] = l; row[9 + c] = h;
    }
    #pragma unroll
    for (int j = 0; j < 8; j++) w0[j] = row[j];
    #pragma unroll
    for (int j = 0; j < 4; j++) w1[j] = row[8 + j];
    unsigned short* dst = pk + (size_t)(b * NN + m) * 40;
    us8 z;
    #pragma unroll
    for (int j = 0; j < 8; j++) z[j] = 0;
    unsigned int ub = __float_as_uint(0.5f * s);
    us8 zh = z;
    zh[0] = (unsigned short)(ub & 0xFFFFu);
    zh[1] = (unsigned short)(ub >> 16);
    *(us8*)(dst) = w0;
    *(us8*)(dst + 8) = w1;
    *(us8*)(dst + 16) = z;
    *(us8*)(dst + 24) = z;
    *(us8*)(dst + 32) = zh;
}

// ---------------- kNN via MFMA (bf16 hi/lo split, 4-term exact) ----------------
// ROUND-7 VERBATIM (best measured: 258us C=64). 64 q/block, 2 blocks/CU,
// double-buffered global_load_lds staging, hn in row pad, exact running tau,
// pool + tid<64 drain, 2 __syncthreads per chunk, XCD pinning.
template<int C>
__global__ __launch_bounds__(256) void knn_kernel(const float* __restrict__ src,
                                                  const unsigned short* __restrict__ pk,
                                                  int* __restrict__ idx) {
    constexpr int SK = (C == 3) ? 40 : (2 * C + 8);   // padded k-stride (shorts)
    constexpr int HNOFF = (C == 3) ? 32 : 2 * C;      // hn fp32 offset in row
    constexpr int UNITS = 8 * SK;                     // 16B units per 64-row chunk
    constexpr int PF = (UNITS + 255) / 256;
    constexpr int KKN = (C == 3) ? 1 : (C / 32);
    __shared__ __attribute__((aligned(16))) unsigned short cpack[2 * 64 * SK];
    __shared__ float pv[64 * 65];
    __shared__ unsigned short pidx[64 * 66];
    __shared__ float tau[64];
    __shared__ int cnt[64];
    __shared__ unsigned short qls[(C == 3) ? 64 * 40 : 2];

    const int bid = blockIdx.x;
    const int b = bid & 7;               // batch -> XCD (wgid % 8 round-robin)
    const int q0 = (bid >> 3) * 64;
    const int tid = threadIdx.x;
    const int lane = tid & 63;
    const int wv = tid >> 6;
    const int wr = (wv >> 1) * 32;      // wave q-offset in [0,64)
    const int wc = (wv & 1) * 32;       // wave m-offset in [0,64)
    const int fl = lane & 15;
    const int fq = lane >> 4;

    float tv[20]; int ti[20];
    #pragma unroll
    for (int k = 0; k < 20; k++) { tv[k] = -3.4e38f; ti[k] = 0; }

    // ---- A fragments (registers, once) ----
    bfrag qah[KKN][2], qal[KKN][2];
    if (C == 3) {
        for (int i = tid; i < 64 * 20; i += 256) {
            int r = i / 20, k = 12 + i % 20;
            qls[r * 40 + k] = 0;
        }
        if (tid < 64) {
            #pragma unroll
            for (int c = 0; c < 3; c++) {
                float v = src[(b * 3 + c) * NN + q0 + tid];
                unsigned short h = bf16rn(v);
                unsigned short l = bf16rn(v - bf16up(h));
                // A-pack: [h3 l3 h3 l3 | 0...] pairs with B-pack [h3 l3 l3 h3]
                qls[tid * 40 + c] = h;  qls[tid * 40 + 3 + c] = l;
                qls[tid * 40 + 6 + c] = h;  qls[tid * 40 + 9 + c] = l;
            }
        }
    } else {
        #pragma unroll
        for (int r2 = 0; r2 < 2; r2++) {
            const unsigned short* qr = pk + (size_t)(b * NN + q0 + wr + r2 * 16 + fl) * SK + fq * 8;
            #pragma unroll
            for (int kk = 0; kk < KKN; kk++) {
                qah[kk][r2] = *(const bfrag*)(qr + kk * 32);
                qal[kk][r2] = *(const bfrag*)(qr + C + kk * 32);
            }
        }
    }

    // ---- prologue: async-stage chunk 0 into buffer 0 ----
    {
        const unsigned short* p0 = pk + (size_t)(b * NN) * SK;
        #pragma unroll
        for (int r = 0; r < PF; r++) {
            int u0 = r * 256 + wv * 64;          // wave-uniform base unit
            if (u0 < UNITS)
                gl_lds16(p0 + (size_t)(u0 + lane) * 8, cpack + (size_t)u0 * 8);
        }
    }
    if (tid < 64) { tau[tid] = -3.4e38f; cnt[tid] = 0; }
    __syncthreads();    // drains vmcnt: chunk 0 resident

    bfrag qa3[2];
    if (C == 3) {
        #pragma unroll
        for (int r2 = 0; r2 < 2; r2++)
            qa3[r2] = *(const bfrag*)(&qls[(wr + r2 * 16 + fl) * 40 + fq * 8]);
    }

    int buf = 0;
    for (int ch = 0; ch < 64; ch++) {
        unsigned short* cur = cpack + buf * (64 * SK);
        // ---- Phase A: issue async stage of ch+1; MFMA + filter on cur ----
        if (ch + 1 < 64) {
            unsigned short* nxt = cpack + (buf ^ 1) * (64 * SK);
            const unsigned short* pn = pk + (size_t)(b * NN + (ch + 1) * 64) * SK;
            #pragma unroll
            for (int r = 0; r < PF; r++) {
                int u0 = r * 256 + wv * 64;
                if (u0 < UNITS)
                    gl_lds16(pn + (size_t)(u0 + lane) * 8, nxt + (size_t)u0 * 8);
            }
        }

        floatx4 acc[2][2];
        #pragma unroll
        for (int r2 = 0; r2 < 2; r2++)
            #pragma unroll
            for (int c2 = 0; c2 < 2; c2++)
                acc[r2][c2] = (floatx4)(0.f);

        if (C == 3) {
            #pragma unroll
            for (int c2 = 0; c2 < 2; c2++) {
                bfrag bm = *(const bfrag*)(&cur[(wc + c2 * 16 + fl) * SK + fq * 8]);
                #pragma unroll
                for (int r2 = 0; r2 < 2; r2++)
                    acc[r2][c2] = __builtin_amdgcn_mfma_f32_16x16x32_bf16(qa3[r2], bm, acc[r2][c2], 0, 0, 0);
            }
        } else {
            #pragma unroll
            for (int kk = 0; kk < KKN; kk++) {
                const int kb = kk * 32 + fq * 8;
                bfrag bh[2], bl[2];
                #pragma unroll
                for (int c2 = 0; c2 < 2; c2++) {
                    bh[c2] = *(const bfrag*)(&cur[(wc + c2 * 16 + fl) * SK + kb]);
                    bl[c2] = *(const bfrag*)(&cur[(wc + c2 * 16 + fl) * SK + C + kb]);
                }
                #pragma unroll
                for (int r2 = 0; r2 < 2; r2++)
                    #pragma unroll
                    for (int c2 = 0; c2 < 2; c2++) {
                        acc[r2][c2] = __builtin_amdgcn_mfma_f32_16x16x32_bf16(qah[kk][r2], bh[c2], acc[r2][c2], 0, 0, 0);
                        acc[r2][c2] = __builtin_amdgcn_mfma_f32_16x16x32_bf16(qah[kk][r2], bl[c2], acc[r2][c2], 0, 0, 0);
                        acc[r2][c2] = __builtin_amdgcn_mfma_f32_16x16x32_bf16(qal[kk][r2], bh[c2], acc[r2][c2], 0, 0, 0);
                        acc[r2][c2] = __builtin_amdgcn_mfma_f32_16x16x32_bf16(qal[kk][r2], bl[c2], acc[r2][c2], 0, 0, 0);
                    }
            }
        }

        // ---- filter: C-layout col=lane&15 (m), row=fq*4+reg (q); exact tau;
        //      hn read from the staged row pad in LDS ----
        {
            const int m0 = ch * 64;
            float hvv[2];
            #pragma unroll
            for (int c2 = 0; c2 < 2; c2++)
                hvv[c2] = *(const float*)(&cur[(wc + c2 * 16 + fl) * SK + HNOFF]);
            #pragma unroll
            for (int r2 = 0; r2 < 2; r2++) {
                const int qb = wr + r2 * 16 + fq * 4;
                float4 t4 = *(const float4*)(&tau[qb]);
                float ta[4] = { t4.x, t4.y, t4.z, t4.w };
                #pragma unroll
                for (int c2 = 0; c2 < 2; c2++) {
                    const float hv = hvv[c2];
                    const int mm = m0 + wc + c2 * 16 + fl;
                    #pragma unroll
                    for (int reg = 0; reg < 4; reg++) {
                        float s = acc[r2][c2][reg] - hv;
                        if (s > ta[reg]) {
                            int q = qb + reg;
                            int p = atomicAdd(&cnt[q], 1);   // <= 64 per chunk: fits
                            pv[q * 65 + p] = s;
                            pidx[q * 66 + p] = (unsigned short)mm;
                        }
                    }
                }
            }
        }
        __syncthreads();   // B1: pool complete; vmcnt(0) -> next chunk resident

        // ---- Phase B: drain (tid<64, lane-parallel over q); exact top-20 + tau ----
        if (tid < 64) {
            int n = cnt[tid];
            for (int t = 0; t < n; t++) {
                float v = pv[tid * 65 + t];
                if (v > tv[0]) {
                    tv[0] = v; ti[0] = (int)pidx[tid * 66 + t];
                    #pragma unroll
                    for (int j = 0; j < 19; j++) {
                        if (tv[j] > tv[j + 1]) {
                            float a = tv[j]; tv[j] = tv[j + 1]; tv[j + 1] = a;
                            int bi = ti[j]; ti[j] = ti[j + 1]; ti[j + 1] = bi;
                        }
                    }
                }
            }
            cnt[tid] = 0;
            tau[tid] = tv[0];
        }
        __syncthreads();   // B2: tau/cnt ready
        buf ^= 1;
    }

    if (tid < 64) {
        #pragma unroll
        for (int k = 0; k < 20; k++)
            idx[(b * NN + q0 + tid) * KK + k] = ti[k];   // order irrelevant downstream
    }
}

// ---------------- conv precompute: G = Wd*src, H = (Wc-Wd)*src ----------------
// XCD-pinned: b = blockIdx.x & 7.
template<int COUT>
__global__ void precompute_kernel(const float* __restrict__ src, int C,
                                  const float* __restrict__ w, int CIN, int wd_off, int wc_off,
                                  float* __restrict__ G, float* __restrict__ H,
                                  int initG, int initH) {
    constexpr int MY = 256 / COUT;
    extern __shared__ float lds[];
    float* wd = lds;
    float* wc = lds + C * COUT;
    const int id = blockIdx.x;
    const int b = id & 7;
    const int m_base = (id >> 3) * 64;
    const int tid = threadIdx.y * COUT + threadIdx.x;
    for (int i = tid; i < C * COUT; i += 256) {
        int c = i / COUT, o = i % COUT;
        float a  = w[o * CIN + wd_off + c];
        float cc = w[o * CIN + wc_off + c];
        wd[i] = a;
        wc[i] = cc - a;
    }
    __syncthreads();
    const int o = threadIdx.x;
    for (int it = 0; it < COUT / 4; it++) {
        int m = m_base + it * MY + threadIdx.y;
        float g = 0.f, h = 0.f;
        for (int c = 0; c < C; c++) {
            float s = src[(b * C + c) * NN + m];
            g += wd[c * COUT + o] * s;
            h += wc[c * COUT + o] * s;
        }
        int gi = (b * NN + m) * COUT + o;
        if (initG) G[gi] = g; else G[gi] += g;
        if (initH) H[gi] = h; else H[gi] += h;
    }
}

// ---------------- conv stats + per-(b,n,o) min/max over k ----------------
// XCD-pinned: b = blockIdx.x & 7 -> batch-b G-rows become L2-resident (1MB/XCD).
template<int COUT, int GROUPS>
__global__ void conv_stats_kernel(const float* __restrict__ G1, const int* __restrict__ idx1,
                                  const float* __restrict__ G2, const int* __restrict__ idx2,
                                  const float* __restrict__ H, float* __restrict__ stats,
                                  float* __restrict__ MaxY, float* __restrict__ MinY) {
    constexpr int NY = 256 / COUT;
    const int id = blockIdx.x;
    const int b = id & 7;
    const int o = threadIdx.x;
    const int n = (id >> 3) * NY + threadIdx.y;
    const int base = b * NN + n;
    const float h = H[base * COUT + o];
    float s1 = 0.f, s2 = 0.f;
    float gx = -3.4e38f, gn = 3.4e38f;
    #pragma unroll
    for (int k = 0; k < KK; k++) {
        int i1 = idx1[base * KK + k];
        float g = G1[(b * NN + i1) * COUT + o];
        if (GROUPS == 2) {
            int i2 = idx2[base * KK + k];
            g += G2[(b * NN + i2) * COUT + o];
        }
        float y = g + h;
        s1 += y;
        s2 += y * y;
        gx = fmaxf(gx, g);
        gn = fminf(gn, g);
    }
    MaxY[base * COUT + o] = gx + h;
    MinY[base * COUT + o] = gn + h;

    __shared__ float ls[2 * COUT];
    if (threadIdx.y == 0) { ls[o] = 0.f; ls[COUT + o] = 0.f; }
    __syncthreads();
    atomicAdd(&ls[o], s1);
    atomicAdd(&ls[COUT + o], s2);
    __syncthreads();
    if (threadIdx.y == 0) {
        atomicAdd(&stats[o], ls[o]);
        atomicAdd(&stats[64 + o], ls[COUT + o]);
    }
}

__global__ void finalize_kernel(const float* __restrict__ g, const float* __restrict__ bb,
                                float* __restrict__ stats, int cout, float invP) {
    int o = threadIdx.x;
    if (o >= cout) return;
    float mu  = stats[o] * invP;
    float var = stats[64 + o] * invP - mu * mu;
    float sc  = g[o] * rsqrtf(var + EPSV);
    stats[128 + o] = sc;
    stats[192 + o] = bb[o] - mu * sc;
}

// XCD-pinned: b = blockIdx.x & 7.
__global__ void apply_kernel(const float* __restrict__ MaxY, const float* __restrict__ MinY,
                             const float* __restrict__ stats, float* __restrict__ out, int cout) {
    const int id = blockIdx.x;
    const int b = id & 7;
    int e = (id >> 3) * 256 + threadIdx.x;
    if (e >= cout * NN) return;
    int n = e & (NN - 1);
    int o = e >> 12;
    float sc = stats[128 + o], sh = stats[192 + o];
    int si = (b * NN + n) * cout + o;
    float v = (sc >= 0.f) ? MaxY[si] : MinY[si];
    out[(b * cout + o) * NN + n] = lrelu(sc * v + sh);
}

__global__ void mean_kernel(const float* __restrict__ xd1, const float* __restrict__ xd2,
                            float* __restrict__ hsum) {
    __shared__ float bins[128];
    const int tid = threadIdx.x;
    if (tid < 128) bins[tid] = 0.f;
    __syncthreads();
    const int half = BB * 64 * NN;
    const int stride = gridDim.x * 256;
    for (int e = blockIdx.x * 256 + tid; e < half; e += stride)
        atomicAdd(&bins[e & 127], xd1[e]);
    for (int e = blockIdx.x * 256 + tid; e < half; e += stride)
        atomicAdd(&bins[e & 127], xd2[e]);
    __syncthreads();
    if (tid < 128) atomicAdd(&hsum[tid], bins[tid]);
}

__global__ void head_kernel(const float* __restrict__ hsum,
                            const float* __restrict__ W2d, const float* __restrict__ b2d,
                            const float* __restrict__ W3d, const float* __restrict__ b3d,
                            const float* __restrict__ W4d, const float* __restrict__ b4d,
                            float* __restrict__ out) {
    __shared__ float h[128], t1[128], t2[64];
    const int t = threadIdx.x;
    h[t] = hsum[t] * (1.f / 32768.f);
    __syncthreads();
    float a = b2d[t];
    for (int j = 0; j < 128; j++) a += W2d[t * 128 + j] * h[j];
    t1[t] = lrelu(a);
    __syncthreads();
    if (t < 64) {
        float a2 = b3d[t];
        for (int j = 0; j < 128; j++) a2 += W3d[t * 128 + j] * t1[j];
        t2[t] = lrelu(a2);
    }
    __syncthreads();
    if (t < 11) {
        float a3 = b4d[t];
        for (int j = 0; j < 64; j++) a3 += W4d[t * 64 + j] * t2[j];
        out[t] = lrelu(a3);
    }
}

extern "C" void kernel_launch(void* const* d_in, const int* in_sizes, int n_in,
                              void* d_out, int out_size, void* d_ws, size_t ws_size,
                              hipStream_t stream) {
    const float* x   = (const float*)d_in[0];
    const float* w1  = (const float*)d_in[1];
    const float* g1  = (const float*)d_in[2];
    const float* b1  = (const float*)d_in[3];
    const float* w2  = (const float*)d_in[4];
    const float* g2  = (const float*)d_in[5];
    const float* b2  = (const float*)d_in[6];
    const float* wd1 = (const float*)d_in[7];
    const float* gd1 = (const float*)d_in[8];
    const float* bd1 = (const float*)d_in[9];
    const float* wd2 = (const float*)d_in[10];
    const float* gd2 = (const float*)d_in[11];
    const float* bd2 = (const float*)d_in[12];
    const float* W2d = (const float*)d_in[13];
    const float* b2d = (const float*)d_in[14];
    const float* W3d = (const float*)d_in[15];
    const float* b3d = (const float*)d_in[16];
    const float* W4d = (const float*)d_in[17];
    const float* b4d = (const float*)d_in[18];
    float* out = (float*)d_out;

    char* ws = (char*)d_ws;
    size_t off = 0;
    auto alloc = [&](size_t bytes) { char* p = ws + off; off += (bytes + 255) & ~size_t(255); return p; };
    int*   idx1  = (int*)  alloc(BB * NN * KK * 4);
    int*   idx2  = (int*)  alloc(BB * NN * KK * 4);
    int*   idx3  = (int*)  alloc(BB * NN * KK * 4);
    float* x1m   = (float*)alloc(BB * 32 * NN * 4);
    float* x2m   = (float*)alloc(BB * 64 * NN * 4);
    float* xd1   = (float*)alloc(BB * 64 * NN * 4);
    float* xd2   = (float*)alloc(BB * 64 * NN * 4);
    float* G1    = (float*)alloc((size_t)BB * NN * 64 * 4);
    float* G2    = (float*)alloc((size_t)BB * NN * 64 * 4);
    float* H     = (float*)alloc((size_t)BB * NN * 64 * 4);
    float* MaxY  = (float*)alloc((size_t)BB * NN * 64 * 4);
    float* MinY  = (float*)alloc((size_t)BB * NN * 64 * 4);
    float* stats = (float*)alloc(4 * 256 * 4);    // 4 slabs: conv1/conv2/convd1/convd2
    float* hsum  = (float*)alloc(128 * 4);

    float* st0 = stats;
    float* st1 = stats + 256;
    float* st2 = stats + 512;
    float* st3 = stats + 768;

    // pk scratch reuses MaxY (+ start of MinY for C=64); dead at every kNN site.
    unsigned short* pkbuf = (unsigned short*)MaxY;

    const float invP = 1.f / (float)(BB * NN * KK);
    const dim3 knn_grid(NN / 64 * BB);     // 1D: b = id & 7 (XCD pinning)
    const dim3 pre_grid(NN / 64 * BB);

    // one upfront zero: 4 stats slabs (1024 floats) + hsum (128), contiguous.
    zero_kernel<<<5, 256, 0, stream>>>(stats, 1024 + 128);

    // --- kNN on x (C=3) ---
    pack3_kernel<<<NN / 256 * BB, 256, 0, stream>>>(x, pkbuf);
    knn_kernel<3><<<knn_grid, 256, 0, stream>>>(x, pkbuf, idx1);

    // --- conv1: Cout=32, group (x, idx1, C=3), w1 CIN=6 ---
    precompute_kernel<32><<<pre_grid, dim3(32, 8), 2 * 3 * 32 * 4, stream>>>(
        x, 3, w1, 6, 0, 3, G1, H, 1, 1);
    conv_stats_kernel<32, 1><<<NN / 8 * BB, dim3(32, 8), 0, stream>>>(
        G1, idx1, nullptr, nullptr, H, st0, MaxY, MinY);
    finalize_kernel<<<1, 64, 0, stream>>>(g1, b1, st0, 32, invP);
    apply_kernel<<<32 * NN / 256 * BB, 256, 0, stream>>>(MaxY, MinY, st0, x1m, 32);

    // --- kNN on x1_max (C=32) ---
    pack_kernel<32><<<pre_grid, 256, 0, stream>>>(x1m, pkbuf);
    knn_kernel<32><<<knn_grid, 256, 0, stream>>>(x1m, pkbuf, idx2);

    // --- conv2: Cout=64, groups (x, idx1, 3) + (x1m, idx2, 32), w2 CIN=70 ---
    precompute_kernel<64><<<pre_grid, dim3(64, 4), 2 * 3 * 64 * 4, stream>>>(
        x, 3, w2, 70, 0, 3, G1, H, 1, 1);
    precompute_kernel<64><<<pre_grid, dim3(64, 4), 2 * 32 * 64 * 4, stream>>>(
        x1m, 32, w2, 70, 6, 38, G2, H, 1, 0);
    conv_stats_kernel<64, 2><<<NN / 4 * BB, dim3(64, 4), 0, stream>>>(
        G1, idx1, G2, idx2, H, st1, MaxY, MinY);
    finalize_kernel<<<1, 64, 0, stream>>>(g2, b2, st1, 64, invP);
    apply_kernel<<<64 * NN / 256 * BB, 256, 0, stream>>>(MaxY, MinY, st1, x2m, 64);

    // --- convd1: Cout=64, group (x1m, idx2, 32), wd1 CIN=64 ---
    precompute_kernel<64><<<pre_grid, dim3(64, 4), 2 * 32 * 64 * 4, stream>>>(
        x1m, 32, wd1, 64, 0, 32, G1, H, 1, 1);
    conv_stats_kernel<64, 1><<<NN / 4 * BB, dim3(64, 4), 0, stream>>>(
        G1, idx2, nullptr, nullptr, H, st2, MaxY, MinY);
    finalize_kernel<<<1, 64, 0, stream>>>(gd1, bd1, st2, 64, invP);
    apply_kernel<<<64 * NN / 256 * BB, 256, 0, stream>>>(MaxY, MinY, st2, xd1, 64);

    // --- kNN on x2_max (C=64) ---
    pack_kernel<64><<<pre_grid, 256, 0, stream>>>(x2m, pkbuf);
    knn_kernel<64><<<knn_grid, 256, 0, stream>>>(x2m, pkbuf, idx3);

    // --- convd2: Cout=64, group (x2m, idx3, 64), wd2 CIN=128 ---
    precompute_kernel<64><<<pre_grid, dim3(64, 4), 2 * 64 * 64 * 4, stream>>>(
        x2m, 64, wd2, 128, 0, 64, G1, H, 1, 1);
    conv_stats_kernel<64, 1><<<NN / 4 * BB, dim3(64, 4), 0, stream>>>(
        G1, idx3, nullptr, nullptr, H, st3, MaxY, MinY);
    finalize_kernel<<<1, 64, 0, stream>>>(gd2, bd2, st3, 64, invP);
    apply_kernel<<<64 * NN / 256 * BB, 256, 0, stream>>>(MaxY, MinY, st3, xd2, 64);

    // --- global mean + MLP head ---
    mean_kernel<<<1024, 256, 0, stream>>>(xd1, xd2, hsum);
    head_kernel<<<1, 128, 0, stream>>>(hsum, W2d, b2d, W3d, b3d, W4d, b4d, out);
}

// Round 12
// 1640.571 us; speedup vs baseline: 1.0870x; 1.0177x over previous
//
#include <hip/hip_runtime.h>

#define BB 8
#define NN 4096
#define KK 20
constexpr float EPSV = 1e-5f;
constexpr float SLOPE = 0.2f;

typedef __bf16 bfrag __attribute__((ext_vector_type(8)));
typedef float floatx4 __attribute__((ext_vector_type(4)));
typedef unsigned short us4 __attribute__((ext_vector_type(4)));
typedef unsigned short us8 __attribute__((ext_vector_type(8)));

__device__ __forceinline__ float lrelu(float v) { return v >= 0.f ? v : SLOPE * v; }

__device__ __forceinline__ unsigned short bf16rn(float f) {
    unsigned int u = __float_as_uint(f);
    return (unsigned short)((u + 0x7FFFu + ((u >> 16) & 1u)) >> 16);
}
__device__ __forceinline__ float bf16up(unsigned short h) {
    return __uint_as_float(((unsigned int)h) << 16);
}

// async global->LDS DMA, 16B per lane; lds dest must be wave-uniform base.
__device__ __forceinline__ void gl_lds16(const unsigned short* g, unsigned short* l) {
    __builtin_amdgcn_global_load_lds((const __attribute__((address_space(1))) void*)g,
                                     (__attribute__((address_space(3))) void*)l, 16, 0, 0);
}

__global__ void zero_kernel(float* p, int n) {
    int i = blockIdx.x * 256 + threadIdx.x;
    if (i < n) p[i] = 0.f;
}

// ---------------- one-shot bf16 hi/lo pack (C>=32), hn fused ----------------
// pk[(b*NN+m)*SK + k]: [0,C)=hi; [C,2C)=lo; [2C,2C+2)=hn fp32 bits; rest 0.
// XCD-pinned: b = blockIdx.x & 7.
template<int C>
__global__ void pack_kernel(const float* __restrict__ src, unsigned short* __restrict__ pk) {
    constexpr int SK = 2 * C + 8;
    const int id = blockIdx.x;
    const int b = id & 7;
    const int m0 = (id >> 3) * 64;
    const int tid = threadIdx.x;
    for (int i = tid; i < 64 * (C / 4); i += 256) {
        int m = i & 63;
        int c4 = (i >> 6) * 4;
        us4 hv, lv;
        #pragma unroll
        for (int j = 0; j < 4; j++) {
            float v = src[(b * C + c4 + j) * NN + m0 + m];
            unsigned short h = bf16rn(v);
            hv[j] = h;
            lv[j] = bf16rn(v - bf16up(h));
        }
        *(us4*)(&pk[(size_t)(b * NN + m0 + m) * SK + c4]) = hv;
        *(us4*)(&pk[(size_t)(b * NN + m0 + m) * SK + C + c4]) = lv;
    }
    if (tid < 64) {
        float s = 0.f;
        for (int c = 0; c < C; c++) {
            float v = src[(b * C + c) * NN + m0 + tid];
            s += v * v;
        }
        unsigned int ub = __float_as_uint(0.5f * s);
        us8 z;
        #pragma unroll
        for (int j = 0; j < 8; j++) z[j] = 0;
        z[0] = (unsigned short)(ub & 0xFFFFu);
        z[1] = (unsigned short)(ub >> 16);
        *(us8*)(&pk[(size_t)(b * NN + m0 + tid) * SK + 2 * C]) = z;
    }
}

// C=3 B-pack: [h3 l3 l3 h3 | 0 x20 | hn fp32 | 0 x6] per point (SK=40), hn inline.
__global__ void pack3_kernel(const float* __restrict__ src, unsigned short* __restrict__ pk) {
    const int id = blockIdx.x;
    const int b = id & 7;
    const int m = (id >> 3) * 256 + threadIdx.x;
    us8 w0, w1;
    #pragma unroll
    for (int j = 0; j < 8; j++) { w0[j] = 0; w1[j] = 0; }
    unsigned short row[12];
    float s = 0.f;
    #pragma unroll
    for (int c = 0; c < 3; c++) {
        float v = src[(b * 3 + c) * NN + m];
        s += v * v;
        unsigned short h = bf16rn(v);
        unsigned short l = bf16rn(v - bf16up(h));
        row[c] = h; row[3 + c] = l; row[6 + c] = l; row[9 + c] = h;
    }
    #pragma unroll
    for (int j = 0; j < 8; j++) w0[j] = row[j];
    #pragma unroll
    for (int j = 0; j < 4; j++) w1[j] = row[8 + j];
    unsigned short* dst = pk + (size_t)(b * NN + m) * 40;
    us8 z;
    #pragma unroll
    for (int j = 0; j < 8; j++) z[j] = 0;
    unsigned int ub = __float_as_uint(0.5f * s);
    us8 zh = z;
    zh[0] = (unsigned short)(ub & 0xFFFFu);
    zh[1] = (unsigned short)(ub >> 16);
    *(us8*)(dst) = w0;
    *(us8*)(dst + 8) = w1;
    *(us8*)(dst + 16) = z;
    *(us8*)(dst + 24) = z;
    *(us8*)(dst + 32) = zh;
}

// ---------------- kNN via MFMA (bf16 hi/lo split, 4-term exact) ----------------
// ROUND-7 VERBATIM (best measured: 258us C=64). 64 q/block, 2 blocks/CU,
// double-buffered global_load_lds staging, hn in row pad, exact running tau,
// pool + tid<64 drain, 2 __syncthreads per chunk, XCD pinning.
template<int C>
__global__ __launch_bounds__(256) void knn_kernel(const float* __restrict__ src,
                                                  const unsigned short* __restrict__ pk,
                                                  int* __restrict__ idx) {
    constexpr int SK = (C == 3) ? 40 : (2 * C + 8);   // padded k-stride (shorts)
    constexpr int HNOFF = (C == 3) ? 32 : 2 * C;      // hn fp32 offset in row
    constexpr int UNITS = 8 * SK;                     // 16B units per 64-row chunk
    constexpr int PF = (UNITS + 255) / 256;
    constexpr int KKN = (C == 3) ? 1 : (C / 32);
    __shared__ __attribute__((aligned(16))) unsigned short cpack[2 * 64 * SK];
    __shared__ float pv[64 * 65];
    __shared__ unsigned short pidx[64 * 66];
    __shared__ float tau[64];
    __shared__ int cnt[64];
    __shared__ unsigned short qls[(C == 3) ? 64 * 40 : 2];

    const int bid = blockIdx.x;
    const int b = bid & 7;               // batch -> XCD (wgid % 8 round-robin)
    const int q0 = (bid >> 3) * 64;
    const int tid = threadIdx.x;
    const int lane = tid & 63;
    const int wv = tid >> 6;
    const int wr = (wv >> 1) * 32;      // wave q-offset in [0,64)
    const int wc = (wv & 1) * 32;       // wave m-offset in [0,64)
    const int fl = lane & 15;
    const int fq = lane >> 4;

    float tv[20]; int ti[20];
    #pragma unroll
    for (int k = 0; k < 20; k++) { tv[k] = -3.4e38f; ti[k] = 0; }

    // ---- A fragments (registers, once) ----
    bfrag qah[KKN][2], qal[KKN][2];
    if (C == 3) {
        for (int i = tid; i < 64 * 20; i += 256) {
            int r = i / 20, k = 12 + i % 20;
            qls[r * 40 + k] = 0;
        }
        if (tid < 64) {
            #pragma unroll
            for (int c = 0; c < 3; c++) {
                float v = src[(b * 3 + c) * NN + q0 + tid];
                unsigned short h = bf16rn(v);
                unsigned short l = bf16rn(v - bf16up(h));
                // A-pack: [h3 l3 h3 l3 | 0...] pairs with B-pack [h3 l3 l3 h3]
                qls[tid * 40 + c] = h;  qls[tid * 40 + 3 + c] = l;
                qls[tid * 40 + 6 + c] = h;  qls[tid * 40 + 9 + c] = l;
            }
        }
    } else {
        #pragma unroll
        for (int r2 = 0; r2 < 2; r2++) {
            const unsigned short* qr = pk + (size_t)(b * NN + q0 + wr + r2 * 16 + fl) * SK + fq * 8;
            #pragma unroll
            for (int kk = 0; kk < KKN; kk++) {
                qah[kk][r2] = *(const bfrag*)(qr + kk * 32);
                qal[kk][r2] = *(const bfrag*)(qr + C + kk * 32);
            }
        }
    }

    // ---- prologue: async-stage chunk 0 into buffer 0 ----
    {
        const unsigned short* p0 = pk + (size_t)(b * NN) * SK;
        #pragma unroll
        for (int r = 0; r < PF; r++) {
            int u0 = r * 256 + wv * 64;          // wave-uniform base unit
            if (u0 < UNITS)
                gl_lds16(p0 + (size_t)(u0 + lane) * 8, cpack + (size_t)u0 * 8);
        }
    }
    if (tid < 64) { tau[tid] = -3.4e38f; cnt[tid] = 0; }
    __syncthreads();    // drains vmcnt: chunk 0 resident

    bfrag qa3[2];
    if (C == 3) {
        #pragma unroll
        for (int r2 = 0; r2 < 2; r2++)
            qa3[r2] = *(const bfrag*)(&qls[(wr + r2 * 16 + fl) * 40 + fq * 8]);
    }

    int buf = 0;
    for (int ch = 0; ch < 64; ch++) {
        unsigned short* cur = cpack + buf * (64 * SK);
        // ---- Phase A: issue async stage of ch+1; MFMA + filter on cur ----
        if (ch + 1 < 64) {
            unsigned short* nxt = cpack + (buf ^ 1) * (64 * SK);
            const unsigned short* pn = pk + (size_t)(b * NN + (ch + 1) * 64) * SK;
            #pragma unroll
            for (int r = 0; r < PF; r++) {
                int u0 = r * 256 + wv * 64;
                if (u0 < UNITS)
                    gl_lds16(pn + (size_t)(u0 + lane) * 8, nxt + (size_t)u0 * 8);
            }
        }

        floatx4 acc[2][2];
        #pragma unroll
        for (int r2 = 0; r2 < 2; r2++)
            #pragma unroll
            for (int c2 = 0; c2 < 2; c2++)
                acc[r2][c2] = (floatx4)(0.f);

        if (C == 3) {
            #pragma unroll
            for (int c2 = 0; c2 < 2; c2++) {
                bfrag bm = *(const bfrag*)(&cur[(wc + c2 * 16 + fl) * SK + fq * 8]);
                #pragma unroll
                for (int r2 = 0; r2 < 2; r2++)
                    acc[r2][c2] = __builtin_amdgcn_mfma_f32_16x16x32_bf16(qa3[r2], bm, acc[r2][c2], 0, 0, 0);
            }
        } else {
            #pragma unroll
            for (int kk = 0; kk < KKN; kk++) {
                const int kb = kk * 32 + fq * 8;
                bfrag bh[2], bl[2];
                #pragma unroll
                for (int c2 = 0; c2 < 2; c2++) {
                    bh[c2] = *(const bfrag*)(&cur[(wc + c2 * 16 + fl) * SK + kb]);
                    bl[c2] = *(const bfrag*)(&cur[(wc + c2 * 16 + fl) * SK + C + kb]);
                }
                #pragma unroll
                for (int r2 = 0; r2 < 2; r2++)
                    #pragma unroll
                    for (int c2 = 0; c2 < 2; c2++) {
                        acc[r2][c2] = __builtin_amdgcn_mfma_f32_16x16x32_bf16(qah[kk][r2], bh[c2], acc[r2][c2], 0, 0, 0);
                        acc[r2][c2] = __builtin_amdgcn_mfma_f32_16x16x32_bf16(qah[kk][r2], bl[c2], acc[r2][c2], 0, 0, 0);
                        acc[r2][c2] = __builtin_amdgcn_mfma_f32_16x16x32_bf16(qal[kk][r2], bh[c2], acc[r2][c2], 0, 0, 0);
                        acc[r2][c2] = __builtin_amdgcn_mfma_f32_16x16x32_bf16(qal[kk][r2], bl[c2], acc[r2][c2], 0, 0, 0);
                    }
            }
        }

        // ---- filter: C-layout col=lane&15 (m), row=fq*4+reg (q); exact tau;
        //      hn read from the staged row pad in LDS ----
        {
            const int m0 = ch * 64;
            float hvv[2];
            #pragma unroll
            for (int c2 = 0; c2 < 2; c2++)
                hvv[c2] = *(const float*)(&cur[(wc + c2 * 16 + fl) * SK + HNOFF]);
            #pragma unroll
            for (int r2 = 0; r2 < 2; r2++) {
                const int qb = wr + r2 * 16 + fq * 4;
                float4 t4 = *(const float4*)(&tau[qb]);
                float ta[4] = { t4.x, t4.y, t4.z, t4.w };
                #pragma unroll
                for (int c2 = 0; c2 < 2; c2++) {
                    const float hv = hvv[c2];
                    const int mm = m0 + wc + c2 * 16 + fl;
                    #pragma unroll
                    for (int reg = 0; reg < 4; reg++) {
                        float s = acc[r2][c2][reg] - hv;
                        if (s > ta[reg]) {
                            int q = qb + reg;
                            int p = atomicAdd(&cnt[q], 1);   // <= 64 per chunk: fits
                            pv[q * 65 + p] = s;
                            pidx[q * 66 + p] = (unsigned short)mm;
                        }
                    }
                }
            }
        }
        __syncthreads();   // B1: pool complete; vmcnt(0) -> next chunk resident

        // ---- Phase B: drain (tid<64, lane-parallel over q); exact top-20 + tau ----
        if (tid < 64) {
            int n = cnt[tid];
            for (int t = 0; t < n; t++) {
                float v = pv[tid * 65 + t];
                if (v > tv[0]) {
                    tv[0] = v; ti[0] = (int)pidx[tid * 66 + t];
                    #pragma unroll
                    for (int j = 0; j < 19; j++) {
                        if (tv[j] > tv[j + 1]) {
                            float a = tv[j]; tv[j] = tv[j + 1]; tv[j + 1] = a;
                            int bi = ti[j]; ti[j] = ti[j + 1]; ti[j + 1] = bi;
                        }
                    }
                }
            }
            cnt[tid] = 0;
            tau[tid] = tv[0];
        }
        __syncthreads();   // B2: tau/cnt ready
        buf ^= 1;
    }

    if (tid < 64) {
        #pragma unroll
        for (int k = 0; k < 20; k++)
            idx[(b * NN + q0 + tid) * KK + k] = ti[k];   // order irrelevant downstream
    }
}

// ---------------- conv precompute: G = Wd*src, H = (Wc-Wd)*src ----------------
// XCD-pinned: b = blockIdx.x & 7.
template<int COUT>
__global__ void precompute_kernel(const float* __restrict__ src, int C,
                                  const float* __restrict__ w, int CIN, int wd_off, int wc_off,
                                  float* __restrict__ G, float* __restrict__ H) {
    constexpr int MY = 256 / COUT;
    extern __shared__ float lds[];
    float* wd = lds;
    float* wc = lds + C * COUT;
    const int id = blockIdx.x;
    const int b = id & 7;
    const int m_base = (id >> 3) * 64;
    const int tid = threadIdx.y * COUT + threadIdx.x;
    for (int i = tid; i < C * COUT; i += 256) {
        int c = i / COUT, o = i % COUT;
        float a  = w[o * CIN + wd_off + c];
        float cc = w[o * CIN + wc_off + c];
        wd[i] = a;
        wc[i] = cc - a;
    }
    __syncthreads();
    const int o = threadIdx.x;
    for (int it = 0; it < COUT / 4; it++) {
        int m = m_base + it * MY + threadIdx.y;
        float g = 0.f, h = 0.f;
        for (int c = 0; c < C; c++) {
            float s = src[(b * C + c) * NN + m];
            g += wd[c * COUT + o] * s;
            h += wc[c * COUT + o] * s;
        }
        int gi = (b * NN + m) * COUT + o;
        G[gi] = g;
        H[gi] = h;
    }
}

// conv2 fused dual-source precompute. CORRECTED vs round 11: writes SEPARATE
// GA (group A: x, offs 0/3) and GB (group B: x1m, offs 6/38) plus combined H,
// so conv_stats<64,2>(GA, idx1, GB, idx2, H) matches the reference exactly.
// Still one pass over both sources, one dispatch, no H read-modify-write.
__global__ void precompute2_kernel(const float* __restrict__ srcA, const float* __restrict__ srcB,
                                   const float* __restrict__ w,
                                   float* __restrict__ GA, float* __restrict__ GB,
                                   float* __restrict__ H) {
    constexpr int COUT = 64, CA = 3, CB = 32, CIN = 70;
    __shared__ float wdA[CA * COUT], wcA[CA * COUT], wdB[CB * COUT], wcB[CB * COUT];
    const int id = blockIdx.x;
    const int b = id & 7;
    const int m_base = (id >> 3) * 64;
    const int tid = threadIdx.y * COUT + threadIdx.x;
    for (int i = tid; i < CA * COUT; i += 256) {
        int c = i / COUT, o = i % COUT;
        float a = w[o * CIN + 0 + c], cc = w[o * CIN + 3 + c];
        wdA[i] = a; wcA[i] = cc - a;
    }
    for (int i = tid; i < CB * COUT; i += 256) {
        int c = i / COUT, o = i % COUT;
        float a = w[o * CIN + 6 + c], cc = w[o * CIN + 38 + c];
        wdB[i] = a; wcB[i] = cc - a;
    }
    __syncthreads();
    const int o = threadIdx.x;
    for (int it = 0; it < 16; it++) {
        int m = m_base + it * 4 + threadIdx.y;
        float ga = 0.f, gb = 0.f, h = 0.f;
        for (int c = 0; c < CA; c++) {
            float s = srcA[(b * CA + c) * NN + m];
            ga += wdA[c * COUT + o] * s;
            h  += wcA[c * COUT + o] * s;
        }
        for (int c = 0; c < CB; c++) {
            float s = srcB[(b * CB + c) * NN + m];
            gb += wdB[c * COUT + o] * s;
            h  += wcB[c * COUT + o] * s;
        }
        int gi = (b * NN + m) * COUT + o;
        GA[gi] = ga;
        GB[gi] = gb;
        H[gi] = h;
    }
}

// ---------------- conv stats + per-(b,n,o) selected extreme over k -------------
// sign(sc) = sign(g[o]) (rsqrt > 0), so the max-vs-min selection is known here:
// write a SINGLE V = chosen extreme + h (MinY eliminated).
// XCD-pinned: b = blockIdx.x & 7 -> batch-b G-rows L2-resident.
template<int COUT, int GROUPS>
__global__ void conv_stats_kernel(const float* __restrict__ G1, const int* __restrict__ idx1,
                                  const float* __restrict__ G2, const int* __restrict__ idx2,
                                  const float* __restrict__ H, const float* __restrict__ gw,
                                  float* __restrict__ stats, float* __restrict__ V) {
    constexpr int NY = 256 / COUT;
    const int id = blockIdx.x;
    const int b = id & 7;
    const int o = threadIdx.x;
    const int n = (id >> 3) * NY + threadIdx.y;
    const int base = b * NN + n;
    const float h = H[base * COUT + o];
    float s1 = 0.f, s2 = 0.f;
    float gx = -3.4e38f, gn = 3.4e38f;
    #pragma unroll
    for (int k = 0; k < KK; k++) {
        int i1 = idx1[base * KK + k];
        float g = G1[(b * NN + i1) * COUT + o];
        if (GROUPS == 2) {
            int i2 = idx2[base * KK + k];
            g += G2[(b * NN + i2) * COUT + o];
        }
        float y = g + h;
        s1 += y;
        s2 += y * y;
        gx = fmaxf(gx, g);
        gn = fminf(gn, g);
    }
    V[base * COUT + o] = ((gw[o] >= 0.f) ? gx : gn) + h;

    __shared__ float ls[2 * COUT];
    if (threadIdx.y == 0) { ls[o] = 0.f; ls[COUT + o] = 0.f; }
    __syncthreads();
    atomicAdd(&ls[o], s1);
    atomicAdd(&ls[COUT + o], s2);
    __syncthreads();
    if (threadIdx.y == 0) {
        atomicAdd(&stats[o], ls[o]);
        atomicAdd(&stats[64 + o], ls[COUT + o]);
    }
}

// apply with fused finalize: o is block-uniform -> thread 0 computes sc/sh from
// raw stat sums, broadcast via LDS. XCD-pinned: b = blockIdx.x & 7.
__global__ void apply_kernel(const float* __restrict__ V, const float* __restrict__ stats,
                             const float* __restrict__ g, const float* __restrict__ bb,
                             float* __restrict__ out, int cout, float invP) {
    const int id = blockIdx.x;
    const int b = id & 7;
    int e = (id >> 3) * 256 + threadIdx.x;
    int n = e & (NN - 1);
    int o = e >> 12;
    __shared__ float sc_s, sh_s;
    if (threadIdx.x == 0) {
        float mu  = stats[o] * invP;
        float var = stats[64 + o] * invP - mu * mu;
        float sc  = g[o] * rsqrtf(var + EPSV);
        sc_s = sc;
        sh_s = bb[o] - mu * sc;
    }
    __syncthreads();
    float v = V[(b * NN + n) * cout + o];
    out[(b * cout + o) * NN + n] = lrelu(sc_s * v + sh_s);
}

__global__ void mean_kernel(const float* __restrict__ xd1, const float* __restrict__ xd2,
                            float* __restrict__ hsum) {
    __shared__ float bins[128];
    const int tid = threadIdx.x;
    if (tid < 128) bins[tid] = 0.f;
    __syncthreads();
    const int half = BB * 64 * NN;
    const int stride = gridDim.x * 256;
    for (int e = blockIdx.x * 256 + tid; e < half; e += stride)
        atomicAdd(&bins[e & 127], xd1[e]);
    for (int e = blockIdx.x * 256 + tid; e < half; e += stride)
        atomicAdd(&bins[e & 127], xd2[e]);
    __syncthreads();
    if (tid < 128) atomicAdd(&hsum[tid], bins[tid]);
}

__global__ void head_kernel(const float* __restrict__ hsum,
                            const float* __restrict__ W2d, const float* __restrict__ b2d,
                            const float* __restrict__ W3d, const float* __restrict__ b3d,
                            const float* __restrict__ W4d, const float* __restrict__ b4d,
                            float* __restrict__ out) {
    __shared__ float h[128], t1[128], t2[64];
    const int t = threadIdx.x;
    h[t] = hsum[t] * (1.f / 32768.f);
    __syncthreads();
    float a = b2d[t];
    for (int j = 0; j < 128; j++) a += W2d[t * 128 + j] * h[j];
    t1[t] = lrelu(a);
    __syncthreads();
    if (t < 64) {
        float a2 = b3d[t];
        for (int j = 0; j < 128; j++) a2 += W3d[t * 128 + j] * t1[j];
        t2[t] = lrelu(a2);
    }
    __syncthreads();
    if (t < 11) {
        float a3 = b4d[t];
        for (int j = 0; j < 64; j++) a3 += W4d[t * 64 + j] * t2[j];
        out[t] = lrelu(a3);
    }
}

extern "C" void kernel_launch(void* const* d_in, const int* in_sizes, int n_in,
                              void* d_out, int out_size, void* d_ws, size_t ws_size,
                              hipStream_t stream) {
    const float* x   = (const float*)d_in[0];
    const float* w1  = (const float*)d_in[1];
    const float* g1  = (const float*)d_in[2];
    const float* b1  = (const float*)d_in[3];
    const float* w2  = (const float*)d_in[4];
    const float* g2  = (const float*)d_in[5];
    const float* b2  = (const float*)d_in[6];
    const float* wd1 = (const float*)d_in[7];
    const float* gd1 = (const float*)d_in[8];
    const float* bd1 = (const float*)d_in[9];
    const float* wd2 = (const float*)d_in[10];
    const float* gd2 = (const float*)d_in[11];
    const float* bd2 = (const float*)d_in[12];
    const float* W2d = (const float*)d_in[13];
    const float* b2d = (const float*)d_in[14];
    const float* W3d = (const float*)d_in[15];
    const float* b3d = (const float*)d_in[16];
    const float* W4d = (const float*)d_in[17];
    const float* b4d = (const float*)d_in[18];
    float* out = (float*)d_out;

    char* ws = (char*)d_ws;
    size_t off = 0;
    auto alloc = [&](size_t bytes) { char* p = ws + off; off += (bytes + 255) & ~size_t(255); return p; };
    int*   idx1  = (int*)  alloc(BB * NN * KK * 4);
    int*   idx2  = (int*)  alloc(BB * NN * KK * 4);
    int*   idx3  = (int*)  alloc(BB * NN * KK * 4);
    float* x1m   = (float*)alloc(BB * 32 * NN * 4);
    float* x2m   = (float*)alloc(BB * 64 * NN * 4);
    float* xd1   = (float*)alloc(BB * 64 * NN * 4);
    float* xd2   = (float*)alloc(BB * 64 * NN * 4);
    float* G1    = (float*)alloc((size_t)BB * NN * 64 * 4);
    float* G2    = (float*)alloc((size_t)BB * NN * 64 * 4);
    float* H     = (float*)alloc((size_t)BB * NN * 64 * 4);
    float* Vbuf  = (float*)alloc((size_t)BB * NN * 64 * 4);
    float* pad   = (float*)alloc((size_t)BB * NN * 64 * 4);   // pk overflow region
    float* stats = (float*)alloc(4 * 256 * 4);    // 4 slabs: conv1/conv2/convd1/convd2
    float* hsum  = (float*)alloc(128 * 4);
    (void)pad;

    float* st0 = stats;
    float* st1 = stats + 256;
    float* st2 = stats + 512;
    float* st3 = stats + 768;

    // pk scratch reuses Vbuf (+ start of pad for C=64); dead at every kNN site.
    unsigned short* pkbuf = (unsigned short*)Vbuf;

    const float invP = 1.f / (float)(BB * NN * KK);
    const dim3 knn_grid(NN / 64 * BB);     // 1D: b = id & 7 (XCD pinning)
    const dim3 pre_grid(NN / 64 * BB);

    // one upfront zero: 4 stats slabs (1024 floats) + hsum (128), contiguous.
    zero_kernel<<<5, 256, 0, stream>>>(stats, 1024 + 128);

    // --- kNN on x (C=3) ---
    pack3_kernel<<<NN / 256 * BB, 256, 0, stream>>>(x, pkbuf);
    knn_kernel<3><<<knn_grid, 256, 0, stream>>>(x, pkbuf, idx1);

    // --- conv1: Cout=32, group (x, idx1, C=3), w1 CIN=6 ---
    precompute_kernel<32><<<pre_grid, dim3(32, 8), 2 * 3 * 32 * 4, stream>>>(
        x, 3, w1, 6, 0, 3, G1, H);
    conv_stats_kernel<32, 1><<<NN / 8 * BB, dim3(32, 8), 0, stream>>>(
        G1, idx1, nullptr, nullptr, H, g1, st0, Vbuf);
    apply_kernel<<<32 * NN / 256 * BB, 256, 0, stream>>>(Vbuf, st0, g1, b1, x1m, 32, invP);

    // --- kNN on x1_max (C=32) ---
    pack_kernel<32><<<pre_grid, 256, 0, stream>>>(x1m, pkbuf);
    knn_kernel<32><<<knn_grid, 256, 0, stream>>>(x1m, pkbuf, idx2);

    // --- conv2: Cout=64, groups (x, idx1, 3) + (x1m, idx2, 32), w2 CIN=70 ---
    // fused dual-source precompute writes SEPARATE G1/G2 + combined H (exact).
    precompute2_kernel<<<pre_grid, dim3(64, 4), 0, stream>>>(x, x1m, w2, G1, G2, H);
    conv_stats_kernel<64, 2><<<NN / 4 * BB, dim3(64, 4), 0, stream>>>(
        G1, idx1, G2, idx2, H, g2, st1, Vbuf);
    apply_kernel<<<64 * NN / 256 * BB, 256, 0, stream>>>(Vbuf, st1, g2, b2, x2m, 64, invP);

    // --- convd1: Cout=64, group (x1m, idx2, 32), wd1 CIN=64 ---
    precompute_kernel<64><<<pre_grid, dim3(64, 4), 2 * 32 * 64 * 4, stream>>>(
        x1m, 32, wd1, 64, 0, 32, G2, H);
    conv_stats_kernel<64, 1><<<NN / 4 * BB, dim3(64, 4), 0, stream>>>(
        G2, idx2, nullptr, nullptr, H, gd1, st2, Vbuf);
    apply_kernel<<<64 * NN / 256 * BB, 256, 0, stream>>>(Vbuf, st2, gd1, bd1, xd1, 64, invP);

    // --- kNN on x2_max (C=64) ---
    pack_kernel<64><<<pre_grid, 256, 0, stream>>>(x2m, pkbuf);
    knn_kernel<64><<<knn_grid, 256, 0, stream>>>(x2m, pkbuf, idx3);

    // --- convd2: Cout=64, group (x2m, idx3, 64), wd2 CIN=128 ---
    precompute_kernel<64><<<pre_grid, dim3(64, 4), 2 * 64 * 64 * 4, stream>>>(
        x2m, 64, wd2, 128, 0, 64, G2, H);
    conv_stats_kernel<64, 1><<<NN / 4 * BB, dim3(64, 4), 0, stream>>>(
        G2, idx3, nullptr, nullptr, H, gd2, st3, Vbuf);
    apply_kernel<<<64 * NN / 256 * BB, 256, 0, stream>>>(Vbuf, st3, gd2, bd2, xd2, 64, invP);

    // --- global mean + MLP head ---
    mean_kernel<<<1024, 256, 0, stream>>>(xd1, xd2, hsum);
    head_kernel<<<1, 128, 0, stream>>>(hsum, W2d, b2d, W3d, b3d, W4d, b4d, out);
}